// Round 1
// baseline (815.467 us; speedup 1.0000x reference)
//
#include <hip/hip_runtime.h>
#include <hip/hip_bf16.h>

#define B_ 4
#define L_ 4096
#define W_ 2560
#define H_ 10
#define NC_ 64   // 64 chunks of 64 tokens

typedef __attribute__((ext_vector_type(8))) short bf16x8;
typedef __attribute__((ext_vector_type(4))) float f32x4;
typedef __attribute__((ext_vector_type(8))) unsigned short u16x8;
typedef __attribute__((ext_vector_type(4))) unsigned short u16x4;

__device__ inline unsigned short f2bf(float f){
  unsigned u = __builtin_bit_cast(unsigned, f);
  u += 0x7fffu + ((u >> 16) & 1u);       // round-to-nearest-even
  return (unsigned short)(u >> 16);
}

// ---------------------------------------------------------------------------
// k_prep: weights f32 -> bf16 in [h][n(512)][k(256)] layout (n<256: w_x col n,
// n>=256: w_a col n-256), plus per-channel softplus(a_param).
// ---------------------------------------------------------------------------
__global__ __launch_bounds__(256) void k_prep(
    const float* __restrict__ w_x, const float* __restrict__ w_a,
    const float* __restrict__ a_param,
    unsigned short* __restrict__ Wt, float* __restrict__ sp_buf){
  int idx = blockIdx.x * 256 + threadIdx.x;
  if (idx < H_ * 512 * 256){
    int k = idx & 255;
    int n = (idx >> 8) & 511;
    int h = idx >> 17;
    float v = (n < 256) ? w_x[((size_t)h * 256 + k) * 256 + n]
                        : w_a[((size_t)h * 256 + k) * 256 + (n - 256)];
    Wt[idx] = f2bf(v);
  }
  if (idx < W_) sp_buf[idx] = log1pf(expf(a_param[idx]));
}

// ---------------------------------------------------------------------------
// k_gates: per block = (batch b, 64-token tile, head h).
// MFMA GEMM: A = x tile [64 x 256] bf16, B = Wt[h] [256 x 512] bf16,
// fused sigmoid/decay/reset elementwise; writes a_buf and nx (into d_out's y).
// 512 threads = 8 waves: wave (wm 0..1, wn 0..3); wave owns [32 rows x 64
// channels x 2 gates] so gate_x/gate_a for a channel live in the same lane.
// ---------------------------------------------------------------------------
__global__ __launch_bounds__(512) void k_gates(
    const float* __restrict__ x, const int* __restrict__ segpos,
    const unsigned short* __restrict__ Wt,
    const float* __restrict__ b_x, const float* __restrict__ b_a,
    const float* __restrict__ sp_buf,
    float* __restrict__ a_buf, float* __restrict__ nx_buf){
  // padded row stride 40 shorts (80B) -> 2-way LDS conflicts only
  __shared__ alignas(16) unsigned short Al[64 * 40];
  __shared__ alignas(16) unsigned short Bl[512 * 40];

  const int bid  = blockIdx.x;
  const int h    = bid % H_;
  const int tile = (bid / H_) & 63;
  const int b    = bid / (H_ * 64);
  const int t0   = tile * 64;
  const int tid  = threadIdx.x;
  const int wave = tid >> 6, lane = tid & 63;
  const int wm = wave >> 2, wn = wave & 3;
  const int lr = lane & 15, hi = lane >> 4;

  const f32x4 zero = {0.f, 0.f, 0.f, 0.f};
  f32x4 accx[2][4], acca[2][4];
  for (int m = 0; m < 2; m++)
    for (int n = 0; n < 4; n++){ accx[m][n] = zero; acca[m][n] = zero; }

  const float* xh = x + ((size_t)b * L_ + t0) * W_ + h * 256;
  const unsigned short* Wh = Wt + (size_t)h * 512 * 256;

  const int arow = tid >> 3, aq = tid & 7;

  for (int kk = 0; kk < 256; kk += 32){
    __syncthreads();
    // stage A tile [64 x 32] f32 -> bf16
    {
      float4 v = *(const float4*)(xh + (size_t)arow * W_ + kk + aq * 4);
      u16x4 p; p.x = f2bf(v.x); p.y = f2bf(v.y); p.z = f2bf(v.z); p.w = f2bf(v.w);
      *(u16x4*)&Al[arow * 40 + aq * 4] = p;
    }
    // stage B tile [512 n rows x 32 k] (already bf16, n-major so k contiguous)
    {
      const unsigned short* src = Wh + (size_t)tid * 256 + kk;
      unsigned short* dst = &Bl[tid * 40];
      *(u16x8*)(dst)      = *(const u16x8*)(src);
      *(u16x8*)(dst + 8)  = *(const u16x8*)(src + 8);
      *(u16x8*)(dst + 16) = *(const u16x8*)(src + 16);
      *(u16x8*)(dst + 24) = *(const u16x8*)(src + 24);
    }
    __syncthreads();

    bf16x8 af[2];
    #pragma unroll
    for (int mf = 0; mf < 2; mf++){
      int row = wm * 32 + mf * 16 + lr;
      af[mf] = *(const bf16x8*)&Al[row * 40 + hi * 8];
    }
    #pragma unroll
    for (int nf = 0; nf < 4; nf++){
      int ncol = wn * 64 + nf * 16 + lr;
      bf16x8 bx = *(const bf16x8*)&Bl[ncol * 40 + hi * 8];
      bf16x8 ba = *(const bf16x8*)&Bl[(ncol + 256) * 40 + hi * 8];
      #pragma unroll
      for (int mf = 0; mf < 2; mf++){
        accx[mf][nf] = __builtin_amdgcn_mfma_f32_16x16x32_bf16(af[mf], bx, accx[mf][nf], 0, 0, 0);
        acca[mf][nf] = __builtin_amdgcn_mfma_f32_16x16x32_bf16(af[mf], ba, acca[mf][nf], 0, 0, 0);
      }
    }
  }

  // epilogue: C/D layout col = lane&15, row = (lane>>4)*4 + i
  #pragma unroll
  for (int nf = 0; nf < 4; nf++){
    const int c_loc = wn * 64 + nf * 16 + lr;
    const int cg = h * 256 + c_loc;
    const float bxv = b_x[h * 256 + c_loc];
    const float bav = b_a[h * 256 + c_loc];
    const float sp  = sp_buf[cg];
    #pragma unroll
    for (int mf = 0; mf < 2; mf++){
      #pragma unroll
      for (int i = 0; i < 4; i++){
        const int t = t0 + wm * 32 + mf * 16 + hi * 4 + i;
        const size_t o = ((size_t)b * L_ + t) * W_ + cg;
        const int seg = segpos[b * L_ + t];
        float zx = accx[mf][nf][i] + bxv;
        float za = acca[mf][nf][i] + bav;
        float gx = 1.f / (1.f + expf(-zx));
        float ga = 1.f / (1.f + expf(-za));
        float la = -8.f * ga * sp;
        float av = expf(la);
        float mult = sqrtf(-expm1f(2.f * la));  // sqrt(1 - a^2), cancellation-safe
        if (seg == 0){ av = 0.f; mult = 1.f; }
        float xv = x[o];
        a_buf[o]  = av;
        nx_buf[o] = xv * gx * mult;
      }
    }
  }
}

// ---------------------------------------------------------------------------
// Phase A: per (b, chunk, 256-channel group): P = prod(a), S = local scan tail
// ---------------------------------------------------------------------------
__global__ __launch_bounds__(256) void k_scanA(
    const float* __restrict__ a_buf, const float* __restrict__ nx_buf,
    float* __restrict__ P_buf, float* __restrict__ S_buf){
  const int bid = blockIdx.x;
  const int cg = bid % (W_ / 256);
  const int ch = (bid / (W_ / 256)) % NC_;
  const int b  = bid / ((W_ / 256) * NC_);
  const int c = cg * 256 + threadIdx.x;
  size_t off = ((size_t)b * L_ + ch * 64) * W_ + c;
  float P = 1.f, S = 0.f;
  #pragma unroll 4
  for (int t = 0; t < 64; t++){
    float a = a_buf[off];
    float v = nx_buf[off];
    S = fmaf(a, S, v);
    P *= a;
    off += W_;
  }
  size_t po = ((size_t)b * NC_ + ch) * W_ + c;
  P_buf[po] = P;
  S_buf[po] = S;
}

// ---------------------------------------------------------------------------
// Phase B: carry scan across 64 chunks per (b, c); final carry == y[:, L-1]
// ---------------------------------------------------------------------------
__global__ __launch_bounds__(256) void k_scanB(
    const float* __restrict__ P_buf, const float* __restrict__ S_buf,
    float* __restrict__ carry_buf, float* __restrict__ y_last){
  const int g = blockIdx.x * 256 + threadIdx.x;  // 0 .. B*W-1
  const int b = g / W_, c = g % W_;
  float carry = 0.f;
  size_t off = (size_t)b * NC_ * W_ + c;
  for (int ch = 0; ch < NC_; ch++){
    carry_buf[off] = carry;
    carry = fmaf(P_buf[off], carry, S_buf[off]);
    off += W_;
  }
  y_last[g] = carry;
}

// ---------------------------------------------------------------------------
// Phase C: re-scan each chunk seeded with its carry; y written in-place over nx
// ---------------------------------------------------------------------------
__global__ __launch_bounds__(256) void k_scanC(
    const float* __restrict__ a_buf, const float* __restrict__ carry_buf,
    float* __restrict__ y){
  const int bid = blockIdx.x;
  const int cg = bid % (W_ / 256);
  const int ch = (bid / (W_ / 256)) % NC_;
  const int b  = bid / ((W_ / 256) * NC_);
  const int c = cg * 256 + threadIdx.x;
  float hcur = carry_buf[((size_t)b * NC_ + ch) * W_ + c];
  size_t off = ((size_t)b * L_ + ch * 64) * W_ + c;
  #pragma unroll 4
  for (int t = 0; t < 64; t++){
    float a = a_buf[off];
    float v = y[off];
    hcur = fmaf(a, hcur, v);
    y[off] = hcur;
    off += W_;
  }
}

extern "C" void kernel_launch(void* const* d_in, const int* in_sizes, int n_in,
                              void* d_out, int out_size, void* d_ws, size_t ws_size,
                              hipStream_t stream){
  (void)in_sizes; (void)n_in; (void)out_size; (void)ws_size;
  const float* x       = (const float*)d_in[0];
  const int*   segpos  = (const int*)d_in[1];
  const float* a_param = (const float*)d_in[2];
  const float* w_x     = (const float*)d_in[3];
  const float* b_x     = (const float*)d_in[4];
  const float* w_a     = (const float*)d_in[5];
  const float* b_a     = (const float*)d_in[6];

  float* y      = (float*)d_out;                 // [B, L, W]
  float* y_last = y + (size_t)B_ * L_ * W_;      // [B, W]

  char* p = (char*)d_ws;
  float* a_buf = (float*)p;                 p += (size_t)B_ * L_ * W_ * 4;   // 167.8 MB
  unsigned short* Wt = (unsigned short*)p;  p += (size_t)H_ * 512 * 256 * 2; // 2.6 MB
  float* sp_buf = (float*)p;                p += (size_t)W_ * 4;
  float* P_buf = (float*)p;                 p += (size_t)B_ * NC_ * W_ * 4;
  float* S_buf = (float*)p;                 p += (size_t)B_ * NC_ * W_ * 4;
  float* carry_buf = (float*)p;             p += (size_t)B_ * NC_ * W_ * 4;

  k_prep<<<dim3((H_ * 512 * 256 + 255) / 256), dim3(256), 0, stream>>>(
      w_x, w_a, a_param, Wt, sp_buf);
  k_gates<<<dim3(B_ * 64 * H_), dim3(512), 0, stream>>>(
      x, segpos, Wt, b_x, b_a, sp_buf, a_buf, y);
  k_scanA<<<dim3(B_ * NC_ * (W_ / 256)), dim3(256), 0, stream>>>(
      a_buf, y, P_buf, S_buf);
  k_scanB<<<dim3((B_ * W_) / 256), dim3(256), 0, stream>>>(
      P_buf, S_buf, carry_buf, y_last);
  k_scanC<<<dim3(B_ * NC_ * (W_ / 256)), dim3(256), 0, stream>>>(
      a_buf, carry_buf, y);
}

// Round 2
// 549.881 us; speedup vs baseline: 1.4830x; 1.4830x over previous
//
#include <hip/hip_runtime.h>
#include <hip/hip_bf16.h>

#define B_ 4
#define L_ 4096
#define W_ 2560
#define H_ 10
#define NC_ 64        // 64 chunks of 64 tokens
#define TRANGE 256    // tokens per k_gates block
#define AL_STRIDE 264 // 256 + 8 shorts pad -> 2-way LDS conflicts only

typedef __attribute__((ext_vector_type(8))) short bf16x8;
typedef __attribute__((ext_vector_type(4))) float f32x4;
typedef __attribute__((ext_vector_type(8))) unsigned short u16x8;
typedef __attribute__((ext_vector_type(4))) unsigned short u16x4;

__device__ inline unsigned short f2bf(float f){
  unsigned u = __builtin_bit_cast(unsigned, f);
  u += 0x7fffu + ((u >> 16) & 1u);       // round-to-nearest-even
  return (unsigned short)(u >> 16);
}

// ---------------------------------------------------------------------------
// k_prep: weights f32 -> bf16 in [h][n(512)][k(256)] layout (n<256: w_x col n,
// n>=256: w_a col n-256), plus per-channel softplus(a_param).
// ---------------------------------------------------------------------------
__global__ __launch_bounds__(256) void k_prep(
    const float* __restrict__ w_x, const float* __restrict__ w_a,
    const float* __restrict__ a_param,
    unsigned short* __restrict__ Wt, float* __restrict__ sp_buf){
  int idx = blockIdx.x * 256 + threadIdx.x;
  if (idx < H_ * 512 * 256){
    int k = idx & 255;
    int n = (idx >> 8) & 511;
    int h = idx >> 17;
    float v = (n < 256) ? w_x[((size_t)h * 256 + k) * 256 + n]
                        : w_a[((size_t)h * 256 + k) * 256 + (n - 256)];
    Wt[idx] = f2bf(v);
  }
  if (idx < W_) sp_buf[idx] = log1pf(expf(a_param[idx]));
}

// ---------------------------------------------------------------------------
// k_gates v2: block = (b, head, channel-half, 256-token range), 512 thr.
// Wave w owns 16 channels (half*128 + w*16 + lr) x 2 gates; B-frags for all
// K=256 live in 64 VGPRs, loaded once. Per 16-token tile: stage A (16x256
// bf16) in LDS, 16 MFMAs/wave, fused sigmoid/decay/reset epilogue, fused
// per-chunk (P, S) segment scan (scanA eliminated).
// ---------------------------------------------------------------------------
__global__ __launch_bounds__(512) void k_gates(
    const float* __restrict__ x, const int* __restrict__ segpos,
    const unsigned short* __restrict__ Wt,
    const float* __restrict__ b_x, const float* __restrict__ b_a,
    const float* __restrict__ sp_buf,
    float* __restrict__ a_buf, float* __restrict__ nx_buf,
    float* __restrict__ P_buf, float* __restrict__ S_buf){
  __shared__ alignas(16) unsigned short Al[16 * AL_STRIDE];

  const int bid   = blockIdx.x;
  const int range = bid & 15;
  const int half  = (bid >> 4) & 1;
  const int rest  = bid >> 5;
  const int h     = rest % H_;
  const int b     = rest / H_;
  const int t_base = range * TRANGE;

  const int tid  = threadIdx.x;
  const int wave = tid >> 6, lane = tid & 63;
  const int lr = lane & 15, hi = lane >> 4;
  const int c_loc = half * 128 + wave * 16 + lr;  // channel within head
  const int cg    = h * 256 + c_loc;              // global channel

  // ---- B fragments in registers: 8 kk-steps x 2 gates x 4 VGPR = 64 VGPR
  const unsigned short* Wh = Wt + (size_t)h * 512 * 256;
  bf16x8 bfx[8], bfa[8];
  #pragma unroll
  for (int k8 = 0; k8 < 8; k8++){
    bfx[k8] = *(const bf16x8*)(Wh + (size_t)c_loc * 256 + k8 * 32 + hi * 8);
    bfa[k8] = *(const bf16x8*)(Wh + (size_t)(c_loc + 256) * 256 + k8 * 32 + hi * 8);
  }
  const float bxv = b_x[h * 256 + c_loc];
  const float bav = b_a[h * 256 + c_loc];
  const float sp  = sp_buf[cg];

  const float* xh = x + ((size_t)b * L_ + t_base) * W_ + h * 256;
  const f32x4 zero = {0.f, 0.f, 0.f, 0.f};

  float Pch = 1.f, Sch = 0.f;   // running chunk scan state (per lane/channel)

  for (int tile = 0; tile < TRANGE / 16; tile++){
    __syncthreads();
    // stage A tile: 16 rows x 256 k, f32 -> bf16. 1024 quads, 2 per thread.
    #pragma unroll
    for (int rep = 0; rep < 2; rep++){
      int Q = tid + rep * 512;
      int row = Q >> 6, kq = Q & 63;
      float4 v = *(const float4*)(xh + (size_t)(tile * 16 + row) * W_ + kq * 4);
      u16x4 p; p.x = f2bf(v.x); p.y = f2bf(v.y); p.z = f2bf(v.z); p.w = f2bf(v.w);
      *(u16x4*)&Al[row * AL_STRIDE + kq * 4] = p;
    }
    __syncthreads();

    f32x4 accx = zero, acca = zero;
    #pragma unroll
    for (int k8 = 0; k8 < 8; k8++){
      bf16x8 af = *(const bf16x8*)&Al[lr * AL_STRIDE + k8 * 32 + hi * 8];
      accx = __builtin_amdgcn_mfma_f32_16x16x32_bf16(af, bfx[k8], accx, 0, 0, 0);
      acca = __builtin_amdgcn_mfma_f32_16x16x32_bf16(af, bfa[k8], acca, 0, 0, 0);
    }

    // ---- epilogue: C/D layout col = lane&15 (channel), row = hi*4+i (token)
    float Pseg = 1.f, Sseg = 0.f;
    #pragma unroll
    for (int i = 0; i < 4; i++){
      const int t = t_base + tile * 16 + hi * 4 + i;
      const size_t o = ((size_t)b * L_ + t) * W_ + cg;
      const int seg = segpos[b * L_ + t];
      float zx = accx[i] + bxv;
      float za = acca[i] + bav;
      float gx = 1.f / (1.f + expf(-zx));
      float ga = 1.f / (1.f + expf(-za));
      float la = -8.f * ga * sp;
      float av = expf(la);
      float mult = sqrtf(-expm1f(2.f * la));   // sqrt(1-a^2), cancellation-safe
      if (seg == 0){ av = 0.f; mult = 1.f; }
      float nxv = x[o] * gx * mult;
      a_buf[o]  = av;
      nx_buf[o] = nxv;
      Sseg = fmaf(av, Sseg, nxv);
      Pseg *= av;
    }
    // ---- ordered cross-hi combine: 4 segments of 4 tokens -> 16 tokens
    {
      float Po = __shfl_xor(Pseg, 16);
      float So = __shfl_xor(Sseg, 16);
      Sseg = (hi & 1) ? fmaf(Pseg, So, Sseg) : fmaf(Po, Sseg, So);
      Pseg = Pseg * Po;
      Po = __shfl_xor(Pseg, 32);
      So = __shfl_xor(Sseg, 32);
      Sseg = ((hi >> 1) & 1) ? fmaf(Pseg, So, Sseg) : fmaf(Po, Sseg, So);
      Pseg = Pseg * Po;
    }
    // ---- accumulate into chunk state (chunk = 4 tiles = 64 tokens)
    Sch = fmaf(Pseg, Sch, Sseg);
    Pch = Pch * Pseg;
    if ((tile & 3) == 3){
      if (hi == 0){
        const int chunk = (t_base >> 6) + (tile >> 2);
        const size_t po = ((size_t)b * NC_ + chunk) * W_ + cg;
        P_buf[po] = Pch;
        S_buf[po] = Sch;
      }
      Pch = 1.f; Sch = 0.f;
    }
  }
}

// ---------------------------------------------------------------------------
// Phase B: carry scan across 64 chunks per (b, c); final carry == y[:, L-1]
// ---------------------------------------------------------------------------
__global__ __launch_bounds__(256) void k_scanB(
    const float* __restrict__ P_buf, const float* __restrict__ S_buf,
    float* __restrict__ carry_buf, float* __restrict__ y_last){
  const int g = blockIdx.x * 256 + threadIdx.x;   // 0 .. B*W/2-1
  const int b = g / (W_ / 2), c2 = g % (W_ / 2);
  float2 carry = {0.f, 0.f};
  size_t off = ((size_t)b * NC_ * W_ + c2 * 2) / 2;
  const float2* P2 = (const float2*)P_buf;
  const float2* S2 = (const float2*)S_buf;
  float2* C2 = (float2*)carry_buf;
  for (int ch = 0; ch < NC_; ch++){
    C2[off] = carry;
    float2 P = P2[off], S = S2[off];
    carry.x = fmaf(P.x, carry.x, S.x);
    carry.y = fmaf(P.y, carry.y, S.y);
    off += W_ / 2;
  }
  *(float2*)&y_last[(size_t)b * W_ + c2 * 2] = carry;
}

// ---------------------------------------------------------------------------
// Phase C: re-scan each chunk seeded with its carry; y in-place over nx.
// 320 threads x float4 = 1280 channels = W/2 per block.
// ---------------------------------------------------------------------------
__global__ __launch_bounds__(320) void k_scanC(
    const float* __restrict__ a_buf, const float* __restrict__ carry_buf,
    float* __restrict__ y){
  const int bid  = blockIdx.x;
  const int half = bid & 1;
  const int ch   = (bid >> 1) % NC_;
  const int b    = bid / (2 * NC_);
  const int c4 = half * 1280 + threadIdx.x * 4;
  float4 hc = *(const float4*)&carry_buf[((size_t)b * NC_ + ch) * W_ + c4];
  size_t off = ((size_t)b * L_ + ch * 64) * W_ + c4;
  #pragma unroll 4
  for (int t = 0; t < 64; t++){
    float4 a = *(const float4*)&a_buf[off];
    float4 v = *(const float4*)&y[off];
    hc.x = fmaf(a.x, hc.x, v.x);
    hc.y = fmaf(a.y, hc.y, v.y);
    hc.z = fmaf(a.z, hc.z, v.z);
    hc.w = fmaf(a.w, hc.w, v.w);
    *(float4*)&y[off] = hc;
    off += W_;
  }
}

extern "C" void kernel_launch(void* const* d_in, const int* in_sizes, int n_in,
                              void* d_out, int out_size, void* d_ws, size_t ws_size,
                              hipStream_t stream){
  (void)in_sizes; (void)n_in; (void)out_size; (void)ws_size;
  const float* x       = (const float*)d_in[0];
  const int*   segpos  = (const int*)d_in[1];
  const float* a_param = (const float*)d_in[2];
  const float* w_x     = (const float*)d_in[3];
  const float* b_x     = (const float*)d_in[4];
  const float* w_a     = (const float*)d_in[5];
  const float* b_a     = (const float*)d_in[6];

  float* y      = (float*)d_out;                 // [B, L, W]
  float* y_last = y + (size_t)B_ * L_ * W_;      // [B, W]

  char* p = (char*)d_ws;
  float* a_buf = (float*)p;                 p += (size_t)B_ * L_ * W_ * 4;   // 167.8 MB
  unsigned short* Wt = (unsigned short*)p;  p += (size_t)H_ * 512 * 256 * 2; // 2.6 MB
  float* sp_buf = (float*)p;                p += (size_t)W_ * 4;
  float* P_buf = (float*)p;                 p += (size_t)B_ * NC_ * W_ * 4;
  float* S_buf = (float*)p;                 p += (size_t)B_ * NC_ * W_ * 4;
  float* carry_buf = (float*)p;             p += (size_t)B_ * NC_ * W_ * 4;

  k_prep<<<dim3((H_ * 512 * 256 + 255) / 256), dim3(256), 0, stream>>>(
      w_x, w_a, a_param, Wt, sp_buf);
  k_gates<<<dim3(B_ * H_ * 2 * (L_ / TRANGE)), dim3(512), 0, stream>>>(
      x, segpos, Wt, b_x, b_a, sp_buf, a_buf, y, P_buf, S_buf);
  k_scanB<<<dim3((B_ * W_ / 2) / 256), dim3(256), 0, stream>>>(
      P_buf, S_buf, carry_buf, y_last);
  k_scanC<<<dim3(B_ * NC_ * 2), dim3(320), 0, stream>>>(
      a_buf, carry_buf, y);
}

// Round 3
// 442.489 us; speedup vs baseline: 1.8429x; 1.2427x over previous
//
#include <hip/hip_runtime.h>
#include <hip/hip_bf16.h>
#include <math.h>

#define B_ 4
#define L_ 4096
#define W_ 2560
#define H_ 10
#define NC_ 64        // 64 chunks of 64 tokens
#define TRANGE 256    // tokens per k_gates block
#define AL_STRIDE 266 // shorts; 133 words === 5 (mod 32) -> ~2-way LDS (free)

typedef __attribute__((ext_vector_type(8))) short bf16x8;
typedef __attribute__((ext_vector_type(4))) float f32x4;
typedef __attribute__((ext_vector_type(4))) unsigned short u16x4;

#define L2E 1.44269504088896f

__device__ inline unsigned short f2bf(float f){
  unsigned u = __builtin_bit_cast(unsigned, f);
  u += 0x7fffu + ((u >> 16) & 1u);       // round-to-nearest-even
  return (unsigned short)(u >> 16);
}
__device__ inline float bf2f(unsigned short s){
  unsigned u = (unsigned)s << 16;
  return __builtin_bit_cast(float, u);
}
__device__ inline float fast_rcp(float x){
#if __has_builtin(__builtin_amdgcn_rcpf)
  return __builtin_amdgcn_rcpf(x);
#else
  return 1.f / x;
#endif
}
__device__ inline float fast_sqrt(float x){
#if __has_builtin(__builtin_amdgcn_sqrtf)
  return __builtin_amdgcn_sqrtf(x);
#else
  return sqrtf(x);
#endif
}
__device__ inline float fast_sigmoid(float z){
  return fast_rcp(1.f + exp2f(-z * L2E));
}

// ---------------------------------------------------------------------------
// k_prep: weights f32 -> bf16 in [h][n(512)][k(256)] layout (n<256: w_x col n,
// n>=256: w_a col n-256); sp2 = -8*log2(e)*softplus(a_param) per channel.
// ---------------------------------------------------------------------------
__global__ __launch_bounds__(256) void k_prep(
    const float* __restrict__ w_x, const float* __restrict__ w_a,
    const float* __restrict__ a_param,
    unsigned short* __restrict__ Wt, float* __restrict__ sp_buf){
  int idx = blockIdx.x * 256 + threadIdx.x;
  if (idx < H_ * 512 * 256){
    int k = idx & 255;
    int n = (idx >> 8) & 511;
    int h = idx >> 17;
    float v = (n < 256) ? w_x[((size_t)h * 256 + k) * 256 + n]
                        : w_a[((size_t)h * 256 + k) * 256 + (n - 256)];
    Wt[idx] = f2bf(v);
  }
  if (idx < W_) sp_buf[idx] = -8.f * L2E * log1pf(expf(a_param[idx]));
}

// ---------------------------------------------------------------------------
// k_gates v3: block = (b, head, channel-half, 256-token range), 512 thr.
// B-frags (K=256, 2 gates) pinned in 64 VGPRs. Per 16-token tile: stage A
// (16x256 bf16) in LDS, 16 MFMAs/wave, fast-transcendental epilogue, packed
// (nx|la2) bf16x2 store, fused per-chunk (P,S) segment scan.
// ---------------------------------------------------------------------------
__global__ __launch_bounds__(512, 4) void k_gates(
    const float* __restrict__ x, const int* __restrict__ segpos,
    const unsigned short* __restrict__ Wt,
    const float* __restrict__ b_x, const float* __restrict__ b_a,
    const float* __restrict__ sp_buf,
    unsigned* __restrict__ pk_buf,
    float* __restrict__ P_buf, float* __restrict__ S_buf){
  __shared__ alignas(16) unsigned short Al[16 * AL_STRIDE];

  const int bid   = blockIdx.x;
  const int range = bid & 15;
  const int half  = (bid >> 4) & 1;
  const int rest  = bid >> 5;
  const int h     = rest % H_;
  const int b     = rest / H_;
  const int t_base = range * TRANGE;

  const int tid  = threadIdx.x;
  const int wave = tid >> 6, lane = tid & 63;
  const int lr = lane & 15, hi = lane >> 4;
  const int c_loc = half * 128 + wave * 16 + lr;  // channel within head
  const int cg    = h * 256 + c_loc;              // global channel

  // ---- B fragments in registers: 8 kk-steps x 2 gates x 4 VGPR = 64 VGPR
  const unsigned short* Wh = Wt + (size_t)h * 512 * 256;
  bf16x8 bfx[8], bfa[8];
  #pragma unroll
  for (int k8 = 0; k8 < 8; k8++){
    bfx[k8] = *(const bf16x8*)(Wh + (size_t)c_loc * 256 + k8 * 32 + hi * 8);
    bfa[k8] = *(const bf16x8*)(Wh + (size_t)(c_loc + 256) * 256 + k8 * 32 + hi * 8);
  }
  const float bxv = b_x[h * 256 + c_loc];
  const float bav = b_a[h * 256 + c_loc];
  const float sp2 = sp_buf[cg];                   // -8*log2e*softplus(a_param)

  const float* xh = x + ((size_t)b * L_ + t_base) * W_ + h * 256;
  const f32x4 zero = {0.f, 0.f, 0.f, 0.f};

  float Pch = 1.f, Sch = 0.f;   // running chunk scan state (per lane/channel)

  for (int tile = 0; tile < TRANGE / 16; tile++){
    __syncthreads();
    // stage A tile: 16 rows x 256 k, f32 -> bf16. 1024 quads, 2 per thread.
    #pragma unroll
    for (int rep = 0; rep < 2; rep++){
      int Q = tid + rep * 512;
      int row = Q >> 6, kq = Q & 63;
      float4 v = *(const float4*)(xh + (size_t)(tile * 16 + row) * W_ + kq * 4);
      u16x4 p; p.x = f2bf(v.x); p.y = f2bf(v.y); p.z = f2bf(v.z); p.w = f2bf(v.w);
      *(u16x4*)&Al[row * AL_STRIDE + kq * 4] = p;
    }
    __syncthreads();

    f32x4 accx = zero, acca = zero;
    #pragma unroll
    for (int k8 = 0; k8 < 8; k8++){
      bf16x8 af = *(const bf16x8*)&Al[lr * AL_STRIDE + k8 * 32 + hi * 8];
      accx = __builtin_amdgcn_mfma_f32_16x16x32_bf16(af, bfx[k8], accx, 0, 0, 0);
      acca = __builtin_amdgcn_mfma_f32_16x16x32_bf16(af, bfa[k8], acca, 0, 0, 0);
    }

    // ---- epilogue: C/D layout col = lane&15 (channel), row = hi*4+i (token)
    float Pseg = 1.f, Sseg = 0.f;
    #pragma unroll
    for (int i = 0; i < 4; i++){
      const int t = t_base + tile * 16 + hi * 4 + i;
      const size_t o = ((size_t)b * L_ + t) * W_ + cg;
      const int seg = segpos[b * L_ + t];
      float gx = fast_sigmoid(accx[i] + bxv);
      float ga = fast_sigmoid(acca[i] + bav);
      float la2 = sp2 * ga;                       // log2(a)
      float av = exp2f(la2);
      float mult = fast_sqrt(fmaf(-av, av, 1.f)); // sqrt(1-a^2)
      if (seg == 0){ av = 0.f; mult = 1.f; la2 = -INFINITY; }
      float xb = bf2f(Al[(hi * 4 + i) * AL_STRIDE + c_loc]);
      float nxv = xb * gx * mult;
      unsigned pk = ((unsigned)f2bf(nxv) << 16) | (unsigned)f2bf(la2);
      pk_buf[o] = pk;
      Sseg = fmaf(av, Sseg, nxv);
      Pseg *= av;
    }
    // ---- ordered cross-hi combine: 4 segments of 4 tokens -> 16 tokens
    {
      float Po = __shfl_xor(Pseg, 16);
      float So = __shfl_xor(Sseg, 16);
      Sseg = (hi & 1) ? fmaf(Pseg, So, Sseg) : fmaf(Po, Sseg, So);
      Pseg = Pseg * Po;
      Po = __shfl_xor(Pseg, 32);
      So = __shfl_xor(Sseg, 32);
      Sseg = ((hi >> 1) & 1) ? fmaf(Pseg, So, Sseg) : fmaf(Po, Sseg, So);
      Pseg = Pseg * Po;
    }
    // ---- accumulate into chunk state (chunk = 4 tiles = 64 tokens)
    Sch = fmaf(Pseg, Sch, Sseg);
    Pch = Pch * Pseg;
    if ((tile & 3) == 3){
      if (hi == 0){
        const int chunk = (t_base >> 6) + (tile >> 2);
        const size_t po = ((size_t)b * NC_ + chunk) * W_ + cg;
        P_buf[po] = Pch;
        S_buf[po] = Sch;
      }
      Pch = 1.f; Sch = 0.f;
    }
  }
}

// ---------------------------------------------------------------------------
// Phase B: carry scan across 64 chunks per (b, c); final carry == y[:, L-1]
// ---------------------------------------------------------------------------
__global__ __launch_bounds__(256) void k_scanB(
    const float* __restrict__ P_buf, const float* __restrict__ S_buf,
    float* __restrict__ carry_buf, float* __restrict__ y_last){
  const int g = blockIdx.x * 256 + threadIdx.x;   // 0 .. B*W/2-1
  const int b = g / (W_ / 2), c2 = g % (W_ / 2);
  float2 carry = {0.f, 0.f};
  size_t off = (size_t)b * NC_ * (W_ / 2) + c2;
  const float2* P2 = (const float2*)P_buf;
  const float2* S2 = (const float2*)S_buf;
  float2* C2 = (float2*)carry_buf;
  for (int ch = 0; ch < NC_; ch++){
    C2[off] = carry;
    float2 P = P2[off], S = S2[off];
    carry.x = fmaf(P.x, carry.x, S.x);
    carry.y = fmaf(P.y, carry.y, S.y);
    off += W_ / 2;
  }
  *(float2*)&y_last[(size_t)b * W_ + c2 * 2] = carry;
}

// ---------------------------------------------------------------------------
// Phase C: re-scan each chunk from packed (nx|la2) seeded with its carry.
// block = (b, chunk, half); 320 thr x 4 channels.
// ---------------------------------------------------------------------------
__global__ __launch_bounds__(320) void k_scanC(
    const unsigned* __restrict__ pk_buf, const float* __restrict__ carry_buf,
    float* __restrict__ y){
  const int bid  = blockIdx.x;
  const int half = bid & 1;
  const int ch   = (bid >> 1) % NC_;
  const int b    = bid / (2 * NC_);
  const int c4 = half * (W_ / 2) + threadIdx.x * 4;
  float4 hc = *(const float4*)&carry_buf[((size_t)b * NC_ + ch) * W_ + c4];
  size_t off = ((size_t)b * L_ + ch * 64) * W_ + c4;
  #pragma unroll 4
  for (int t = 0; t < 64; t++){
    uint4 pk = *(const uint4*)&pk_buf[off];
    float4 out;
    {
      float a  = exp2f(__builtin_bit_cast(float, pk.x << 16));
      float nx = __builtin_bit_cast(float, pk.x & 0xFFFF0000u);
      out.x = hc.x = fmaf(a, hc.x, nx);
    }
    {
      float a  = exp2f(__builtin_bit_cast(float, pk.y << 16));
      float nx = __builtin_bit_cast(float, pk.y & 0xFFFF0000u);
      out.y = hc.y = fmaf(a, hc.y, nx);
    }
    {
      float a  = exp2f(__builtin_bit_cast(float, pk.z << 16));
      float nx = __builtin_bit_cast(float, pk.z & 0xFFFF0000u);
      out.z = hc.z = fmaf(a, hc.z, nx);
    }
    {
      float a  = exp2f(__builtin_bit_cast(float, pk.w << 16));
      float nx = __builtin_bit_cast(float, pk.w & 0xFFFF0000u);
      out.w = hc.w = fmaf(a, hc.w, nx);
    }
    *(float4*)&y[off] = out;
    off += W_;
  }
}

extern "C" void kernel_launch(void* const* d_in, const int* in_sizes, int n_in,
                              void* d_out, int out_size, void* d_ws, size_t ws_size,
                              hipStream_t stream){
  (void)in_sizes; (void)n_in; (void)out_size; (void)ws_size;
  const float* x       = (const float*)d_in[0];
  const int*   segpos  = (const int*)d_in[1];
  const float* a_param = (const float*)d_in[2];
  const float* w_x     = (const float*)d_in[3];
  const float* b_x     = (const float*)d_in[4];
  const float* w_a     = (const float*)d_in[5];
  const float* b_a     = (const float*)d_in[6];

  float* y      = (float*)d_out;                 // [B, L, W]
  float* y_last = y + (size_t)B_ * L_ * W_;      // [B, W]

  char* p = (char*)d_ws;
  unsigned* pk_buf = (unsigned*)p;          p += (size_t)B_ * L_ * W_ * 4;   // 167.8 MB
  unsigned short* Wt = (unsigned short*)p;  p += (size_t)H_ * 512 * 256 * 2; // 2.6 MB
  float* sp_buf = (float*)p;                p += (size_t)W_ * 4;
  float* P_buf = (float*)p;                 p += (size_t)B_ * NC_ * W_ * 4;
  float* S_buf = (float*)p;                 p += (size_t)B_ * NC_ * W_ * 4;
  float* carry_buf = (float*)p;             p += (size_t)B_ * NC_ * W_ * 4;

  k_prep<<<dim3((H_ * 512 * 256 + 255) / 256), dim3(256), 0, stream>>>(
      w_x, w_a, a_param, Wt, sp_buf);
  k_gates<<<dim3(B_ * H_ * 2 * (L_ / TRANGE)), dim3(512), 0, stream>>>(
      x, segpos, Wt, b_x, b_a, sp_buf, pk_buf, P_buf, S_buf);
  k_scanB<<<dim3((B_ * W_ / 2) / 256), dim3(256), 0, stream>>>(
      P_buf, S_buf, carry_buf, y_last);
  k_scanC<<<dim3(B_ * NC_ * 2), dim3(320), 0, stream>>>(
      pk_buf, carry_buf, y);
}